// Round 1
// baseline (537.599 us; speedup 1.0000x reference)
//
#include <hip/hip_runtime.h>

#define S_LEN 4096
#define DMODEL 1024
#define NH 16
#define NKV 4
#define HDIM 64
#define NQKV 1536  /* (16+2*4)*64 */

typedef __attribute__((ext_vector_type(8))) short bfrag8;
typedef __attribute__((ext_vector_type(4))) float f32x4_t;

__device__ __forceinline__ unsigned short f2bf(float f) {
  unsigned int u = __builtin_bit_cast(unsigned int, f);
  return (unsigned short)((u + 0x7fffu + ((u >> 16) & 1u)) >> 16);
}

// ---------------- elementwise f32 -> bf16 ----------------
__global__ void convert_bf16(const float* __restrict__ in, unsigned short* __restrict__ out, int n) {
  int idx = (blockIdx.x * 256 + threadIdx.x) * 4;
  if (idx < n) {
    float4 v = *reinterpret_cast<const float4*>(in + idx);
    out[idx + 0] = f2bf(v.x);
    out[idx + 1] = f2bf(v.y);
    out[idx + 2] = f2bf(v.z);
    out[idx + 3] = f2bf(v.w);
  }
}

// ---------------- tiled transpose + convert: out[c][r] = bf16(in[r][c]) ----------------
__global__ void transpose_convert(const float* __restrict__ in, int ldin, long in_zstride,
                                  unsigned short* __restrict__ out, int ldout, long out_zstride,
                                  int R, int C) {
  __shared__ float tile[32][33];
  const float* inb = in + (size_t)blockIdx.z * in_zstride;
  unsigned short* outb = out + (size_t)blockIdx.z * out_zstride;
  int c0 = blockIdx.x * 32, r0 = blockIdx.y * 32;
  int tx = threadIdx.x, ty = threadIdx.y;  // 32 x 8
  for (int i = 0; i < 4; ++i) {
    int r = r0 + ty + i * 8;
    tile[ty + i * 8][tx] = inb[(size_t)r * ldin + c0 + tx];
  }
  __syncthreads();
  for (int i = 0; i < 4; ++i) {
    int c = c0 + ty + i * 8;
    outb[(size_t)c * ldout + r0 + tx] = f2bf(tile[tx][ty + i * 8]);
  }
}

// ---------------- RoPE on Q and K sections of qkv (f32 in), scatter to per-head bf16 ----------------
__global__ void rope_kernel(const float* __restrict__ qkv,
                            const float* __restrict__ pcos, const float* __restrict__ psin,
                            unsigned short* __restrict__ Qh, unsigned short* __restrict__ Kh) {
  int s = blockIdx.x;
  int t = threadIdx.x;
  const float* row = qkv + (size_t)s * NQKV;
  for (int p = t; p < 640; p += 256) {
    int i = p & 31;
    float c = pcos[s * 32 + i], sn = psin[s * 32 + i];
    if (p < 512) {
      int h = p >> 5;
      float te = row[h * 64 + 2 * i], to = row[h * 64 + 2 * i + 1];
      size_t base = ((size_t)h * S_LEN + s) * 64;
      Qh[base + 2 * i]     = f2bf(te * c - to * sn);
      Qh[base + 2 * i + 1] = f2bf(te * sn + to * c);
    } else {
      int hk = (p - 512) >> 5;
      float te = row[1024 + hk * 64 + 2 * i], to = row[1024 + hk * 64 + 2 * i + 1];
      size_t base = ((size_t)hk * S_LEN + s) * 64;
      Kh[base + 2 * i]     = f2bf(te * c - to * sn);
      Kh[base + 2 * i + 1] = f2bf(te * sn + to * c);
    }
  }
}

// ---------------- bf16 MFMA GEMM: C(MxN,f32) = A(MxK) * Bt(NxK)^T ----------------
#define BM 128
#define BN 128
#define BK 32
#define LDSW 40  // padded LDS row stride (elements); 80B = 5*16B keeps 16B alignment

__global__ __launch_bounds__(256) void gemm_bf16(
    const unsigned short* __restrict__ A,
    const unsigned short* __restrict__ Bt,
    float* __restrict__ C, int M, int N, int K) {
  __shared__ unsigned short As[BM * LDSW];
  __shared__ unsigned short Bs[BN * LDSW];
  int m0 = blockIdx.x * BM, n0 = blockIdx.y * BN;
  int t = threadIdx.x, lane = t & 63, wid = t >> 6;
  int wm = (wid >> 1) * 64, wn = (wid & 1) * 64;
  int fr = lane & 15, kb = lane >> 4;
  f32x4_t acc[4][4];
  for (int r = 0; r < 4; ++r)
    for (int c = 0; c < 4; ++c) acc[r][c] = (f32x4_t){0.f, 0.f, 0.f, 0.f};

  for (int k0 = 0; k0 < K; k0 += BK) {
    __syncthreads();
    for (int i = 0; i < 2; ++i) {
      int idx = (i * 256 + t) * 8;
      int r = idx >> 5, c = idx & 31;
      bfrag8 va = *reinterpret_cast<const bfrag8*>(A + (size_t)(m0 + r) * K + k0 + c);
      *reinterpret_cast<bfrag8*>(&As[r * LDSW + c]) = va;
      bfrag8 vb = *reinterpret_cast<const bfrag8*>(Bt + (size_t)(n0 + r) * K + k0 + c);
      *reinterpret_cast<bfrag8*>(&Bs[r * LDSW + c]) = vb;
    }
    __syncthreads();
    bfrag8 af[4], bfr[4];
    for (int rb = 0; rb < 4; ++rb)
      af[rb] = *reinterpret_cast<const bfrag8*>(&As[(wm + rb * 16 + fr) * LDSW + kb * 8]);
    for (int cb = 0; cb < 4; ++cb)
      bfr[cb] = *reinterpret_cast<const bfrag8*>(&Bs[(wn + cb * 16 + fr) * LDSW + kb * 8]);
    for (int rb = 0; rb < 4; ++rb)
      for (int cb = 0; cb < 4; ++cb)
        acc[rb][cb] = __builtin_amdgcn_mfma_f32_16x16x32_bf16(af[rb], bfr[cb], acc[rb][cb], 0, 0, 0);
  }
  int rowg = (lane >> 4) * 4, colg = lane & 15;
  for (int rb = 0; rb < 4; ++rb)
    for (int cb = 0; cb < 4; ++cb)
      for (int j = 0; j < 4; ++j) {
        int r = m0 + wm + rb * 16 + rowg + j;
        int c = n0 + wn + cb * 16 + colg;
        C[(size_t)r * N + c] = acc[rb][cb][j];
      }
}

// ---------------- flash attention: causal, GQA ----------------
// Qh [NH][S][64], Kh [NKV][S][64], Vt [NKV][64][S], aout [S][NH*64] bf16
__global__ __launch_bounds__(256) void flash_attn(
    const unsigned short* __restrict__ Qh,
    const unsigned short* __restrict__ Kh,
    const unsigned short* __restrict__ Vt,
    unsigned short* __restrict__ aout) {
  __shared__ unsigned short Pl[4][16 * 40];
  int h = blockIdx.y, hk = h >> 2;
  int q0 = blockIdx.x * 64;
  int t = threadIdx.x, lane = t & 63, wid = t >> 6;
  int qrow0 = q0 + wid * 16;
  int fr = lane & 15, kb = lane >> 4;
  int rloc = kb * 4;

  const unsigned short* Qbase = Qh + ((size_t)h * S_LEN + qrow0) * 64;
  bfrag8 qf0 = *reinterpret_cast<const bfrag8*>(Qbase + fr * 64 + kb * 8);
  bfrag8 qf1 = *reinterpret_cast<const bfrag8*>(Qbase + fr * 64 + 32 + kb * 8);

  float m_r[4], l_r[4];
  f32x4_t acc[4];
  for (int j = 0; j < 4; ++j) { m_r[j] = -1e30f; l_r[j] = 0.f; }
  for (int dt = 0; dt < 4; ++dt) acc[dt] = (f32x4_t){0.f, 0.f, 0.f, 0.f};

  int nkt = (q0 + 64) / 32;
  for (int kt = 0; kt < nkt; ++kt) {
    int kv0 = kt * 32;
    f32x4_t sc[2];
    for (int ct = 0; ct < 2; ++ct) {
      const unsigned short* Kbase = Kh + ((size_t)hk * S_LEN + kv0 + ct * 16) * 64;
      bfrag8 b0 = *reinterpret_cast<const bfrag8*>(Kbase + fr * 64 + kb * 8);
      bfrag8 b1 = *reinterpret_cast<const bfrag8*>(Kbase + fr * 64 + 32 + kb * 8);
      f32x4_t z = (f32x4_t){0.f, 0.f, 0.f, 0.f};
      sc[ct] = __builtin_amdgcn_mfma_f32_16x16x32_bf16(qf0, b0, z, 0, 0, 0);
      sc[ct] = __builtin_amdgcn_mfma_f32_16x16x32_bf16(qf1, b1, sc[ct], 0, 0, 0);
    }
    // scale + causal mask + row max (rows are lane-local: row = rloc+j, col = fr)
    float alpha[4];
    for (int j = 0; j < 4; ++j) {
      int grow = qrow0 + rloc + j;
      float mx = -1e30f;
      for (int ct = 0; ct < 2; ++ct) {
        int gcol = kv0 + ct * 16 + fr;
        float v = sc[ct][j] * 0.125f;
        v = (gcol <= grow) ? v : -1e30f;
        sc[ct][j] = v;
        mx = fmaxf(mx, v);
      }
      for (int d = 1; d < 16; d <<= 1) mx = fmaxf(mx, __shfl_xor(mx, d));
      float mnew = fmaxf(m_r[j], mx);
      alpha[j] = __expf(m_r[j] - mnew);
      m_r[j] = mnew;
      float s = 0.f;
      for (int ct = 0; ct < 2; ++ct) {
        float p = __expf(sc[ct][j] - mnew);
        sc[ct][j] = p;
        s += p;
      }
      for (int d = 1; d < 16; d <<= 1) s += __shfl_xor(s, d);
      l_r[j] = l_r[j] * alpha[j] + s;
    }
    for (int dt = 0; dt < 4; ++dt)
      for (int j = 0; j < 4; ++j) acc[dt][j] *= alpha[j];
    // P -> LDS (bf16), reshape D-layout -> A-layout
    for (int ct = 0; ct < 2; ++ct)
      for (int j = 0; j < 4; ++j)
        Pl[wid][(rloc + j) * 40 + ct * 16 + fr] = f2bf(sc[ct][j]);
    __syncthreads();
    bfrag8 pa = *reinterpret_cast<const bfrag8*>(&Pl[wid][fr * 40 + kb * 8]);
    for (int dt = 0; dt < 4; ++dt) {
      const unsigned short* Vb = Vt + (size_t)hk * 64 * S_LEN + (size_t)(dt * 16 + fr) * S_LEN + kv0 + kb * 8;
      bfrag8 bv = *reinterpret_cast<const bfrag8*>(Vb);
      acc[dt] = __builtin_amdgcn_mfma_f32_16x16x32_bf16(pa, bv, acc[dt], 0, 0, 0);
    }
    __syncthreads();
  }
  for (int dt = 0; dt < 4; ++dt)
    for (int j = 0; j < 4; ++j) {
      int grow = qrow0 + rloc + j;
      float o = acc[dt][j] / l_r[j];
      aout[(size_t)grow * (NH * HDIM) + h * 64 + dt * 16 + fr] = f2bf(o);
    }
}

// ---------------- launch ----------------
extern "C" void kernel_launch(void* const* d_in, const int* in_sizes, int n_in,
                              void* d_out, int out_size, void* d_ws, size_t ws_size,
                              hipStream_t stream) {
  const float* x    = (const float*)d_in[0];
  const float* pcos = (const float*)d_in[1];
  const float* psin = (const float*)d_in[2];
  const float* wqkv = (const float*)d_in[3];
  const float* wo   = (const float*)d_in[4];
  float* out = (float*)d_out;

  char* ws = (char*)d_ws;
  unsigned short* xb    = (unsigned short*)ws;  ws += (size_t)S_LEN * DMODEL * 2;      // 8 MB
  unsigned short* wqkvT = (unsigned short*)ws;  ws += (size_t)NQKV * DMODEL * 2;       // 3 MB
  unsigned short* woT   = (unsigned short*)ws;  ws += (size_t)DMODEL * DMODEL * 2;     // 2 MB
  float*          qkv   = (float*)ws;           ws += (size_t)S_LEN * NQKV * 4;        // 24 MB
  unsigned short* Qh    = (unsigned short*)ws;  ws += (size_t)NH * S_LEN * HDIM * 2;   // 8 MB
  unsigned short* Kh    = (unsigned short*)ws;  ws += (size_t)NKV * S_LEN * HDIM * 2;  // 2 MB
  unsigned short* Vt    = (unsigned short*)ws;  ws += (size_t)NKV * HDIM * S_LEN * 2;  // 2 MB
  unsigned short* aoutb = (unsigned short*)ws;  ws += (size_t)S_LEN * NH * HDIM * 2;   // 8 MB

  // 1. x -> bf16
  convert_bf16<<<(S_LEN * DMODEL) / (256 * 4), 256, 0, stream>>>(x, xb, S_LEN * DMODEL);
  // 2. weight transposes
  transpose_convert<<<dim3(NQKV / 32, DMODEL / 32, 1), dim3(32, 8), 0, stream>>>(
      wqkv, NQKV, 0, wqkvT, DMODEL, 0, DMODEL, NQKV);
  transpose_convert<<<dim3(DMODEL / 32, DMODEL / 32, 1), dim3(32, 8), 0, stream>>>(
      wo, DMODEL, 0, woT, DMODEL, 0, DMODEL, DMODEL);
  // 3. qkv = x @ w_qkv  (f32 out)
  gemm_bf16<<<dim3(S_LEN / BM, NQKV / BN), 256, 0, stream>>>(xb, wqkvT, qkv, S_LEN, NQKV, DMODEL);
  // 4. RoPE -> Qh, Kh ; V -> Vt (transposed per kv head)
  rope_kernel<<<S_LEN, 256, 0, stream>>>(qkv, pcos, psin, Qh, Kh);
  transpose_convert<<<dim3(HDIM / 32, S_LEN / 32, NKV), dim3(32, 8), 0, stream>>>(
      qkv + 1280, NQKV, 64, Vt, S_LEN, (long)HDIM * S_LEN, S_LEN, HDIM);
  // 5. attention
  flash_attn<<<dim3(S_LEN / 64, NH), 256, 0, stream>>>(Qh, Kh, Vt, aoutb);
  // 6. out = attn @ w_o
  gemm_bf16<<<dim3(S_LEN / BM, DMODEL / BN), 256, 0, stream>>>(aoutb, woT, out, S_LEN, DMODEL, DMODEL);
}

// Round 2
// 472.947 us; speedup vs baseline: 1.1367x; 1.1367x over previous
//
#include <hip/hip_runtime.h>

#define S_LEN 4096
#define DMODEL 1024
#define NH 16
#define NKV 4
#define HDIM 64
#define NQKV 1536  /* (16+2*4)*64 */

typedef __attribute__((ext_vector_type(8))) short bfrag8;
typedef __attribute__((ext_vector_type(4))) float f32x4_t;

__device__ __forceinline__ unsigned short f2bf(float f) {
  unsigned int u = __builtin_bit_cast(unsigned int, f);
  return (unsigned short)((u + 0x7fffu + ((u >> 16) & 1u)) >> 16);
}

// ---------------- elementwise f32 -> bf16 ----------------
__global__ void convert_bf16(const float* __restrict__ in, unsigned short* __restrict__ out, int n) {
  int idx = (blockIdx.x * 256 + threadIdx.x) * 4;
  if (idx < n) {
    float4 v = *reinterpret_cast<const float4*>(in + idx);
    out[idx + 0] = f2bf(v.x);
    out[idx + 1] = f2bf(v.y);
    out[idx + 2] = f2bf(v.z);
    out[idx + 3] = f2bf(v.w);
  }
}

// ---------------- tiled transpose + convert: out[c][r] = bf16(in[r][c]) ----------------
__global__ void transpose_convert(const float* __restrict__ in, int ldin, long in_zstride,
                                  unsigned short* __restrict__ out, int ldout, long out_zstride,
                                  int R, int C) {
  __shared__ float tile[32][33];
  const float* inb = in + (size_t)blockIdx.z * in_zstride;
  unsigned short* outb = out + (size_t)blockIdx.z * out_zstride;
  int c0 = blockIdx.x * 32, r0 = blockIdx.y * 32;
  int tx = threadIdx.x, ty = threadIdx.y;  // 32 x 8
  for (int i = 0; i < 4; ++i) {
    int r = r0 + ty + i * 8;
    tile[ty + i * 8][tx] = inb[(size_t)r * ldin + c0 + tx];
  }
  __syncthreads();
  for (int i = 0; i < 4; ++i) {
    int c = c0 + ty + i * 8;
    outb[(size_t)c * ldout + r0 + tx] = f2bf(tile[tx][ty + i * 8]);
  }
}

// ---------------- RoPE on Q and K sections of qkv (f32 in), scatter to per-head bf16 ----------------
__global__ void rope_kernel(const float* __restrict__ qkv,
                            const float* __restrict__ pcos, const float* __restrict__ psin,
                            unsigned short* __restrict__ Qh, unsigned short* __restrict__ Kh) {
  int s = blockIdx.x;
  int t = threadIdx.x;
  const float* row = qkv + (size_t)s * NQKV;
  for (int p = t; p < 640; p += 256) {
    int i = p & 31;
    float c = pcos[s * 32 + i], sn = psin[s * 32 + i];
    if (p < 512) {
      int h = p >> 5;
      float te = row[h * 64 + 2 * i], to = row[h * 64 + 2 * i + 1];
      size_t base = ((size_t)h * S_LEN + s) * 64;
      Qh[base + 2 * i]     = f2bf(te * c - to * sn);
      Qh[base + 2 * i + 1] = f2bf(te * sn + to * c);
    } else {
      int hk = (p - 512) >> 5;
      float te = row[1024 + hk * 64 + 2 * i], to = row[1024 + hk * 64 + 2 * i + 1];
      size_t base = ((size_t)hk * S_LEN + s) * 64;
      Kh[base + 2 * i]     = f2bf(te * c - to * sn);
      Kh[base + 2 * i + 1] = f2bf(te * sn + to * c);
    }
  }
}

// ---------------- bf16 MFMA GEMM: C(MxN,f32) = A(MxK) * Bt(NxK)^T ----------------
#define BM 128
#define BN 128
#define BK 32
#define LDSW 40  // padded LDS row stride (elements); 80B = 5*16B keeps 16B alignment

__global__ __launch_bounds__(256) void gemm_bf16(
    const unsigned short* __restrict__ A,
    const unsigned short* __restrict__ Bt,
    float* __restrict__ C, int M, int N, int K) {
  __shared__ unsigned short As[BM * LDSW];
  __shared__ unsigned short Bs[BN * LDSW];
  int m0 = blockIdx.x * BM, n0 = blockIdx.y * BN;
  int t = threadIdx.x, lane = t & 63, wid = t >> 6;
  int wm = (wid >> 1) * 64, wn = (wid & 1) * 64;
  int fr = lane & 15, kb = lane >> 4;
  f32x4_t acc[4][4];
  for (int r = 0; r < 4; ++r)
    for (int c = 0; c < 4; ++c) acc[r][c] = (f32x4_t){0.f, 0.f, 0.f, 0.f};

  for (int k0 = 0; k0 < K; k0 += BK) {
    __syncthreads();
    for (int i = 0; i < 2; ++i) {
      int idx = (i * 256 + t) * 8;
      int r = idx >> 5, c = idx & 31;
      bfrag8 va = *reinterpret_cast<const bfrag8*>(A + (size_t)(m0 + r) * K + k0 + c);
      *reinterpret_cast<bfrag8*>(&As[r * LDSW + c]) = va;
      bfrag8 vb = *reinterpret_cast<const bfrag8*>(Bt + (size_t)(n0 + r) * K + k0 + c);
      *reinterpret_cast<bfrag8*>(&Bs[r * LDSW + c]) = vb;
    }
    __syncthreads();
    bfrag8 af[4], bfr[4];
    for (int rb = 0; rb < 4; ++rb)
      af[rb] = *reinterpret_cast<const bfrag8*>(&As[(wm + rb * 16 + fr) * LDSW + kb * 8]);
    for (int cb = 0; cb < 4; ++cb)
      bfr[cb] = *reinterpret_cast<const bfrag8*>(&Bs[(wn + cb * 16 + fr) * LDSW + kb * 8]);
    for (int rb = 0; rb < 4; ++rb)
      for (int cb = 0; cb < 4; ++cb)
        acc[rb][cb] = __builtin_amdgcn_mfma_f32_16x16x32_bf16(af[rb], bfr[cb], acc[rb][cb], 0, 0, 0);
  }
  int rowg = (lane >> 4) * 4, colg = lane & 15;
  for (int rb = 0; rb < 4; ++rb)
    for (int cb = 0; cb < 4; ++cb)
      for (int j = 0; j < 4; ++j) {
        int r = m0 + wm + rb * 16 + rowg + j;
        int c = n0 + wn + cb * 16 + colg;
        C[(size_t)r * N + c] = acc[rb][cb][j];
      }
}

// ---------------- flash attention: causal, GQA, KVBLK=64, no barriers ----------------
// Qh [NH][S][64], Kh [NKV][S][64], Vt [NKV][64][S], aout [S][NH*64] bf16
#define PLDS 72  // padded P row stride (shorts); 144B = 9*16B keeps 16B alignment

__global__ __launch_bounds__(256) void flash_attn(
    const unsigned short* __restrict__ Qh,
    const unsigned short* __restrict__ Kh,
    const unsigned short* __restrict__ Vt,
    unsigned short* __restrict__ aout) {
  __shared__ unsigned short Pl[4][16 * PLDS];
  int h = blockIdx.y, hk = h >> 2;
  int qblk = gridDim.x - 1 - blockIdx.x;  // largest causal blocks dispatch first
  int q0 = qblk * 64;
  int t = threadIdx.x, lane = t & 63, wid = t >> 6;
  int qrow0 = q0 + wid * 16;
  int fr = lane & 15, kb = lane >> 4;
  int rloc = kb * 4;
  unsigned short* Pw = &Pl[wid][0];

  const unsigned short* Qbase = Qh + ((size_t)h * S_LEN + qrow0) * 64;
  bfrag8 qf0 = *reinterpret_cast<const bfrag8*>(Qbase + fr * 64 + kb * 8);
  bfrag8 qf1 = *reinterpret_cast<const bfrag8*>(Qbase + fr * 64 + 32 + kb * 8);

  const unsigned short* Kbh = Kh + (size_t)hk * S_LEN * 64;
  const unsigned short* Vbh = Vt + (size_t)hk * 64 * S_LEN;

  float m_r[4], l_r[4];
  f32x4_t acc[4];
#pragma unroll
  for (int j = 0; j < 4; ++j) { m_r[j] = -1e30f; l_r[j] = 0.f; }
#pragma unroll
  for (int dt = 0; dt < 4; ++dt) acc[dt] = (f32x4_t){0.f, 0.f, 0.f, 0.f};

  const float SCL = 0.125f * 1.44269504f;  // scale * log2(e): exp2 domain

  int nt = (qrow0 + 16 + 63) / 64;                      // total kv tiles for this wave
  int nf = (qrow0 >= 63) ? ((qrow0 - 63) / 64 + 1) : 0; // fully-unmasked tiles

  auto tile_step = [&](int kv0, bool domask) {
    // ---- preload K and V fragments (latency hides under softmax) ----
    bfrag8 kf[4][2], vf[2][4];
#pragma unroll
    for (int ct = 0; ct < 4; ++ct) {
      const unsigned short* Kb = Kbh + (size_t)(kv0 + ct * 16 + fr) * 64 + kb * 8;
      kf[ct][0] = *reinterpret_cast<const bfrag8*>(Kb);
      kf[ct][1] = *reinterpret_cast<const bfrag8*>(Kb + 32);
    }
#pragma unroll
    for (int hh = 0; hh < 2; ++hh)
#pragma unroll
      for (int dt = 0; dt < 4; ++dt)
        vf[hh][dt] = *reinterpret_cast<const bfrag8*>(
            Vbh + (size_t)(dt * 16 + fr) * S_LEN + kv0 + hh * 32 + kb * 8);
    // ---- QK^T ----
    f32x4_t sc[4];
#pragma unroll
    for (int ct = 0; ct < 4; ++ct) {
      f32x4_t z = (f32x4_t){0.f, 0.f, 0.f, 0.f};
      z = __builtin_amdgcn_mfma_f32_16x16x32_bf16(qf0, kf[ct][0], z, 0, 0, 0);
      sc[ct] = __builtin_amdgcn_mfma_f32_16x16x32_bf16(qf1, kf[ct][1], z, 0, 0, 0);
    }
    // ---- online softmax (rows lane-local: row = rloc+j, col = ct*16+fr) ----
    float alpha[4];
    bool up = false;
#pragma unroll
    for (int j = 0; j < 4; ++j) {
      int grow = qrow0 + rloc + j;
#pragma unroll
      for (int ct = 0; ct < 4; ++ct) {
        float v = sc[ct][j] * SCL;
        if (domask) v = ((kv0 + ct * 16 + fr) <= grow) ? v : -1e30f;
        sc[ct][j] = v;
      }
      float mx = fmaxf(fmaxf(sc[0][j], sc[1][j]), fmaxf(sc[2][j], sc[3][j]));
#pragma unroll
      for (int d = 1; d < 16; d <<= 1) mx = fmaxf(mx, __shfl_xor(mx, d));
      float mnew = fmaxf(m_r[j], mx);
      up = up || (mx > m_r[j]);
      alpha[j] = exp2f(m_r[j] - mnew);
      m_r[j] = mnew;
      float s = 0.f;
#pragma unroll
      for (int ct = 0; ct < 4; ++ct) {
        float p = exp2f(sc[ct][j] - mnew);
        sc[ct][j] = p;
        s += p;
      }
#pragma unroll
      for (int d = 1; d < 16; d <<= 1) s += __shfl_xor(s, d);
      l_r[j] = l_r[j] * alpha[j] + s;
    }
    if (__any(up)) {
#pragma unroll
      for (int dt = 0; dt < 4; ++dt)
#pragma unroll
        for (int j = 0; j < 4; ++j) acc[dt][j] *= alpha[j];
    }
    // ---- P -> per-wave LDS (D-layout -> A-layout), bf16 ----
#pragma unroll
    for (int ct = 0; ct < 4; ++ct)
#pragma unroll
      for (int j = 0; j < 4; ++j)
        Pw[(rloc + j) * PLDS + ct * 16 + fr] = f2bf(sc[ct][j]);
    // ---- PV ----
#pragma unroll
    for (int hh = 0; hh < 2; ++hh) {
      bfrag8 pa = *reinterpret_cast<const bfrag8*>(Pw + fr * PLDS + hh * 32 + kb * 8);
#pragma unroll
      for (int dt = 0; dt < 4; ++dt)
        acc[dt] = __builtin_amdgcn_mfma_f32_16x16x32_bf16(pa, vf[hh][dt], acc[dt], 0, 0, 0);
    }
  };

  for (int kt = 0; kt < nf; ++kt) tile_step(kt * 64, false);
  for (int kt = nf; kt < nt; ++kt) tile_step(kt * 64, true);

#pragma unroll
  for (int dt = 0; dt < 4; ++dt)
#pragma unroll
    for (int j = 0; j < 4; ++j) {
      int grow = qrow0 + rloc + j;
      float o = acc[dt][j] / l_r[j];
      aout[(size_t)grow * (NH * HDIM) + h * 64 + dt * 16 + fr] = f2bf(o);
    }
}

// ---------------- launch ----------------
extern "C" void kernel_launch(void* const* d_in, const int* in_sizes, int n_in,
                              void* d_out, int out_size, void* d_ws, size_t ws_size,
                              hipStream_t stream) {
  const float* x    = (const float*)d_in[0];
  const float* pcos = (const float*)d_in[1];
  const float* psin = (const float*)d_in[2];
  const float* wqkv = (const float*)d_in[3];
  const float* wo   = (const float*)d_in[4];
  float* out = (float*)d_out;

  char* ws = (char*)d_ws;
  unsigned short* xb    = (unsigned short*)ws;  ws += (size_t)S_LEN * DMODEL * 2;      // 8 MB
  unsigned short* wqkvT = (unsigned short*)ws;  ws += (size_t)NQKV * DMODEL * 2;       // 3 MB
  unsigned short* woT   = (unsigned short*)ws;  ws += (size_t)DMODEL * DMODEL * 2;     // 2 MB
  float*          qkv   = (float*)ws;           ws += (size_t)S_LEN * NQKV * 4;        // 24 MB
  unsigned short* Qh    = (unsigned short*)ws;  ws += (size_t)NH * S_LEN * HDIM * 2;   // 8 MB
  unsigned short* Kh    = (unsigned short*)ws;  ws += (size_t)NKV * S_LEN * HDIM * 2;  // 2 MB
  unsigned short* Vt    = (unsigned short*)ws;  ws += (size_t)NKV * HDIM * S_LEN * 2;  // 2 MB
  unsigned short* aoutb = (unsigned short*)ws;  ws += (size_t)S_LEN * NH * HDIM * 2;   // 8 MB

  // 1. x -> bf16
  convert_bf16<<<(S_LEN * DMODEL) / (256 * 4), 256, 0, stream>>>(x, xb, S_LEN * DMODEL);
  // 2. weight transposes
  transpose_convert<<<dim3(NQKV / 32, DMODEL / 32, 1), dim3(32, 8), 0, stream>>>(
      wqkv, NQKV, 0, wqkvT, DMODEL, 0, DMODEL, NQKV);
  transpose_convert<<<dim3(DMODEL / 32, DMODEL / 32, 1), dim3(32, 8), 0, stream>>>(
      wo, DMODEL, 0, woT, DMODEL, 0, DMODEL, DMODEL);
  // 3. qkv = x @ w_qkv  (f32 out)
  gemm_bf16<<<dim3(S_LEN / BM, NQKV / BN), 256, 0, stream>>>(xb, wqkvT, qkv, S_LEN, NQKV, DMODEL);
  // 4. RoPE -> Qh, Kh ; V -> Vt (transposed per kv head)
  rope_kernel<<<S_LEN, 256, 0, stream>>>(qkv, pcos, psin, Qh, Kh);
  transpose_convert<<<dim3(HDIM / 32, S_LEN / 32, NKV), dim3(32, 8), 0, stream>>>(
      qkv + 1280, NQKV, 64, Vt, S_LEN, (long)HDIM * S_LEN, S_LEN, HDIM);
  // 5. attention
  flash_attn<<<dim3(S_LEN / 64, NH), 256, 0, stream>>>(Qh, Kh, Vt, aoutb);
  // 6. out = attn @ w_o
  gemm_bf16<<<dim3(S_LEN / BM, DMODEL / BN), 256, 0, stream>>>(aoutb, woT, out, S_LEN, DMODEL, DMODEL);
}

// Round 3
// 410.171 us; speedup vs baseline: 1.3107x; 1.1530x over previous
//
#include <hip/hip_runtime.h>

#define S_LEN 4096
#define DMODEL 1024
#define NH 16
#define NKV 4
#define HDIM 64
#define NQKV 1536  /* (16+2*4)*64 */

typedef __attribute__((ext_vector_type(8))) short bfrag8;
typedef __attribute__((ext_vector_type(4))) float f32x4_t;

__device__ __forceinline__ unsigned short f2bf(float f) {
  unsigned int u = __builtin_bit_cast(unsigned int, f);
  return (unsigned short)((u + 0x7fffu + ((u >> 16) & 1u)) >> 16);
}

// ---------------- elementwise f32 -> bf16 ----------------
__global__ void convert_bf16(const float* __restrict__ in, unsigned short* __restrict__ out, int n) {
  int idx = (blockIdx.x * 256 + threadIdx.x) * 4;
  if (idx < n) {
    float4 v = *reinterpret_cast<const float4*>(in + idx);
    out[idx + 0] = f2bf(v.x);
    out[idx + 1] = f2bf(v.y);
    out[idx + 2] = f2bf(v.z);
    out[idx + 3] = f2bf(v.w);
  }
}

// ---------------- tiled transpose + convert: out[c][r] = bf16(in[r][c]) ----------------
__global__ void transpose_convert(const float* __restrict__ in, int ldin, long in_zstride,
                                  unsigned short* __restrict__ out, int ldout, long out_zstride,
                                  int R, int C) {
  __shared__ float tile[32][33];
  const float* inb = in + (size_t)blockIdx.z * in_zstride;
  unsigned short* outb = out + (size_t)blockIdx.z * out_zstride;
  int c0 = blockIdx.x * 32, r0 = blockIdx.y * 32;
  int tx = threadIdx.x, ty = threadIdx.y;  // 32 x 8
  for (int i = 0; i < 4; ++i) {
    int r = r0 + ty + i * 8;
    tile[ty + i * 8][tx] = inb[(size_t)r * ldin + c0 + tx];
  }
  __syncthreads();
  for (int i = 0; i < 4; ++i) {
    int c = c0 + ty + i * 8;
    outb[(size_t)c * ldout + r0 + tx] = f2bf(tile[tx][ty + i * 8]);
  }
}

// ---------------- RoPE; Q pre-scaled by 0.125*log2(e) so QK^T lands in exp2 domain ----------------
__global__ void rope_kernel(const float* __restrict__ qkv,
                            const float* __restrict__ pcos, const float* __restrict__ psin,
                            unsigned short* __restrict__ Qh, unsigned short* __restrict__ Kh) {
  const float SCL = 0.125f * 1.44269504f;
  int s = blockIdx.x;
  int t = threadIdx.x;
  const float* row = qkv + (size_t)s * NQKV;
  for (int p = t; p < 640; p += 256) {
    int i = p & 31;
    float c = pcos[s * 32 + i], sn = psin[s * 32 + i];
    if (p < 512) {
      int h = p >> 5;
      float te = row[h * 64 + 2 * i], to = row[h * 64 + 2 * i + 1];
      size_t base = ((size_t)h * S_LEN + s) * 64;
      Qh[base + 2 * i]     = f2bf((te * c - to * sn) * SCL);
      Qh[base + 2 * i + 1] = f2bf((te * sn + to * c) * SCL);
    } else {
      int hk = (p - 512) >> 5;
      float te = row[1024 + hk * 64 + 2 * i], to = row[1024 + hk * 64 + 2 * i + 1];
      size_t base = ((size_t)hk * S_LEN + s) * 64;
      Kh[base + 2 * i]     = f2bf(te * c - to * sn);
      Kh[base + 2 * i + 1] = f2bf(te * sn + to * c);
    }
  }
}

// ---------------- bf16 MFMA GEMM: C(MxN,f32) = A(MxK) * Bt(NxK)^T ----------------
#define BM 128
#define BN 128
#define BK 32
#define LDSW 40

__global__ __launch_bounds__(256) void gemm_bf16(
    const unsigned short* __restrict__ A,
    const unsigned short* __restrict__ Bt,
    float* __restrict__ C, int M, int N, int K) {
  __shared__ unsigned short As[BM * LDSW];
  __shared__ unsigned short Bs[BN * LDSW];
  int m0 = blockIdx.x * BM, n0 = blockIdx.y * BN;
  int t = threadIdx.x, lane = t & 63, wid = t >> 6;
  int wm = (wid >> 1) * 64, wn = (wid & 1) * 64;
  int fr = lane & 15, kb = lane >> 4;
  f32x4_t acc[4][4];
  for (int r = 0; r < 4; ++r)
    for (int c = 0; c < 4; ++c) acc[r][c] = (f32x4_t){0.f, 0.f, 0.f, 0.f};

  for (int k0 = 0; k0 < K; k0 += BK) {
    __syncthreads();
    for (int i = 0; i < 2; ++i) {
      int idx = (i * 256 + t) * 8;
      int r = idx >> 5, c = idx & 31;
      bfrag8 va = *reinterpret_cast<const bfrag8*>(A + (size_t)(m0 + r) * K + k0 + c);
      *reinterpret_cast<bfrag8*>(&As[r * LDSW + c]) = va;
      bfrag8 vb = *reinterpret_cast<const bfrag8*>(Bt + (size_t)(n0 + r) * K + k0 + c);
      *reinterpret_cast<bfrag8*>(&Bs[r * LDSW + c]) = vb;
    }
    __syncthreads();
    bfrag8 af[4], bfr[4];
    for (int rb = 0; rb < 4; ++rb)
      af[rb] = *reinterpret_cast<const bfrag8*>(&As[(wm + rb * 16 + fr) * LDSW + kb * 8]);
    for (int cb = 0; cb < 4; ++cb)
      bfr[cb] = *reinterpret_cast<const bfrag8*>(&Bs[(wn + cb * 16 + fr) * LDSW + kb * 8]);
    for (int rb = 0; rb < 4; ++rb)
      for (int cb = 0; cb < 4; ++cb)
        acc[rb][cb] = __builtin_amdgcn_mfma_f32_16x16x32_bf16(af[rb], bfr[cb], acc[rb][cb], 0, 0, 0);
  }
  int rowg = (lane >> 4) * 4, colg = lane & 15;
  for (int rb = 0; rb < 4; ++rb)
    for (int cb = 0; cb < 4; ++cb)
      for (int j = 0; j < 4; ++j) {
        int r = m0 + wm + rb * 16 + rowg + j;
        int c = n0 + wn + cb * 16 + colg;
        C[(size_t)r * N + c] = acc[rb][cb][j];
      }
}

// ---------------- flash attention: causal, GQA, swapped-QK^T, KV-split x2 ----------------
// Qh [NH][S][64] (pre-scaled), Kh [NKV][S][64], Vt [NKV][64][S], aout [S][NH*64] bf16
// Block: 256 thr = 4 waves = 2 q-tiles (16 rows each) x 2 KV-halves.
#define PLDS 72

__global__ __launch_bounds__(256, 4) void flash_attn(
    const unsigned short* __restrict__ Qh,
    const unsigned short* __restrict__ Kh,
    const unsigned short* __restrict__ Vt,
    unsigned short* __restrict__ aout) {
  __shared__ unsigned short Pl[4][16 * PLDS];
  __shared__ float ACCs[2][16][64];  // [qslot][reg=dt*4+j][lane]
  __shared__ float MLs[2][2][16];    // [qslot][{m,l}][row]

  int h = blockIdx.y, hk = h >> 2;
  int bq = gridDim.x - 1 - blockIdx.x;  // biggest chains dispatch first
  int t = threadIdx.x, lane = t & 63, wid = t >> 6;
  int qsel = wid & 1, half = wid >> 1;
  int qt = bq * 2 + qsel;
  int qrow0 = qt * 16;
  int fr = lane & 15, kb = lane >> 4, rloc = kb * 4;
  unsigned short* Pw = &Pl[wid][0];

  // Q B-frags (same memory layout as before; consumed as MFMA B operand now)
  const unsigned short* Qbase = Qh + ((size_t)h * S_LEN + qrow0) * 64;
  bfrag8 qf0 = *reinterpret_cast<const bfrag8*>(Qbase + fr * 64 + kb * 8);
  bfrag8 qf1 = *reinterpret_cast<const bfrag8*>(Qbase + fr * 64 + 32 + kb * 8);

  const unsigned short* Kbh = Kh + (size_t)hk * S_LEN * 64;
  const unsigned short* Vbh = Vt + (size_t)hk * 64 * S_LEN;

  // softmax state: lane fr owns q-row fr (uniform across kb groups)
  float m_r = -1e30f, l_r = 0.f;
  f32x4_t acc[4];
#pragma unroll
  for (int dt = 0; dt < 4; ++dt) acc[dt] = (f32x4_t){0.f, 0.f, 0.f, 0.f};

  int ntt = (qrow0 + 79) / 64;                          // total KV tiles for this q-tile
  int nh0 = (ntt + 1) >> 1;                             // first-half tile count
  int nf = (qrow0 >= 63) ? ((qrow0 - 63) / 64 + 1) : 0; // fully-unmasked tiles

  auto tile_step = [&](int kv0, bool domask) {
    // preload K and V fragments
    bfrag8 kf[4][2], vf[2][4];
#pragma unroll
    for (int ct = 0; ct < 4; ++ct) {
      const unsigned short* Kb = Kbh + (size_t)(kv0 + ct * 16 + fr) * 64 + kb * 8;
      kf[ct][0] = *reinterpret_cast<const bfrag8*>(Kb);
      kf[ct][1] = *reinterpret_cast<const bfrag8*>(Kb + 32);
    }
#pragma unroll
    for (int hh = 0; hh < 2; ++hh)
#pragma unroll
      for (int dt = 0; dt < 4; ++dt)
        vf[hh][dt] = *reinterpret_cast<const bfrag8*>(
            Vbh + (size_t)(dt * 16 + fr) * S_LEN + kv0 + hh * 32 + kb * 8);
    // swapped QK^T: D[m=kcol][n=qrow] -> lane (kb,fr) holds q-row fr, kcols ct*16+kb*4+j
    f32x4_t sc[4];
#pragma unroll
    for (int ct = 0; ct < 4; ++ct) {
      f32x4_t z = (f32x4_t){0.f, 0.f, 0.f, 0.f};
      z = __builtin_amdgcn_mfma_f32_16x16x32_bf16(kf[ct][0], qf0, z, 0, 0, 0);
      sc[ct] = __builtin_amdgcn_mfma_f32_16x16x32_bf16(kf[ct][1], qf1, sc[ct] = z, 0, 0, 0);
    }
    if (domask) {
      int grow = qrow0 + fr;
#pragma unroll
      for (int ct = 0; ct < 4; ++ct)
#pragma unroll
        for (int j = 0; j < 4; ++j)
          sc[ct][j] = ((kv0 + ct * 16 + kb * 4 + j) <= grow) ? sc[ct][j] : -1e30f;
    }
    // row max: lane-local tree + 2 shuffles across kb groups
    float pm0 = fmaxf(fmaxf(sc[0][0], sc[0][1]), fmaxf(sc[0][2], sc[0][3]));
    float pm1 = fmaxf(fmaxf(sc[1][0], sc[1][1]), fmaxf(sc[1][2], sc[1][3]));
    float pm2 = fmaxf(fmaxf(sc[2][0], sc[2][1]), fmaxf(sc[2][2], sc[2][3]));
    float pm3 = fmaxf(fmaxf(sc[3][0], sc[3][1]), fmaxf(sc[3][2], sc[3][3]));
    float pmax = fmaxf(fmaxf(pm0, pm1), fmaxf(pm2, pm3));
    pmax = fmaxf(pmax, __shfl_xor(pmax, 16));
    pmax = fmaxf(pmax, __shfl_xor(pmax, 32));
    // defer-max: only rescale when max rose by > 8 (exp2 domain)
    if (__any(pmax > m_r + 8.0f)) {
      float mnew = fmaxf(m_r, pmax);
      float a = exp2f(m_r - mnew);
      l_r *= a;
      m_r = mnew;
#pragma unroll
      for (int j = 0; j < 4; ++j) {
        float aj = __shfl(a, rloc + j);
#pragma unroll
        for (int dt = 0; dt < 4; ++dt) acc[dt][j] *= aj;
      }
    }
    // P = exp2(s - m), lane-local row sum + 2 shuffles
    float s = 0.f;
#pragma unroll
    for (int ct = 0; ct < 4; ++ct) {
#pragma unroll
      for (int j = 0; j < 4; ++j) {
        float p = exp2f(sc[ct][j] - m_r);
        sc[ct][j] = p;
        s += p;
      }
    }
    s += __shfl_xor(s, 16);
    s += __shfl_xor(s, 32);
    l_r += s;
    // P -> per-wave LDS: row q=fr, cols ct*16+kb*4+{0..3}; packed b64 writes
#pragma unroll
    for (int ct = 0; ct < 4; ++ct) {
      unsigned int u01 = (unsigned int)f2bf(sc[ct][0]) | ((unsigned int)f2bf(sc[ct][1]) << 16);
      unsigned int u23 = (unsigned int)f2bf(sc[ct][2]) | ((unsigned int)f2bf(sc[ct][3]) << 16);
      unsigned long long w = ((unsigned long long)u23 << 32) | u01;
      *reinterpret_cast<unsigned long long*>(&Pw[fr * PLDS + ct * 16 + kb * 4]) = w;
    }
    // PV: A = P (rows=q), B = V
#pragma unroll
    for (int hh = 0; hh < 2; ++hh) {
      bfrag8 pa = *reinterpret_cast<const bfrag8*>(Pw + fr * PLDS + hh * 32 + kb * 8);
#pragma unroll
      for (int dt = 0; dt < 4; ++dt)
        acc[dt] = __builtin_amdgcn_mfma_f32_16x16x32_bf16(pa, vf[hh][dt], acc[dt], 0, 0, 0);
    }
  };

  int kstart = half ? nh0 : 0;
  int kend = half ? ntt : nh0;
  int kmid = min(kend, nf);
  for (int kt = kstart; kt < kmid; ++kt) tile_step(kt * 64, false);
  for (int kt = max(kstart, nf); kt < kend; ++kt) tile_step(kt * 64, true);

  // merge the two KV halves
  if (half == 1) {
#pragma unroll
    for (int dt = 0; dt < 4; ++dt)
#pragma unroll
      for (int j = 0; j < 4; ++j) ACCs[qsel][dt * 4 + j][lane] = acc[dt][j];
    if (kb == 0) {
      MLs[qsel][0][fr] = m_r;
      MLs[qsel][1][fr] = l_r;
    }
  }
  __syncthreads();
  if (half == 0) {
    float m1 = MLs[qsel][0][fr], l1 = MLs[qsel][1][fr];
    float mm = fmaxf(m_r, m1);
    float c0 = exp2f(m_r - mm), c1 = exp2f(m1 - mm);
    float inv = 1.0f / (l_r * c0 + l1 * c1);
#pragma unroll
    for (int j = 0; j < 4; ++j) {
      float c0j = __shfl(c0, rloc + j);
      float c1j = __shfl(c1, rloc + j);
      float invj = __shfl(inv, rloc + j);
      int grow = qrow0 + rloc + j;
#pragma unroll
      for (int dt = 0; dt < 4; ++dt) {
        float a1 = ACCs[qsel][dt * 4 + j][lane];
        float o = (acc[dt][j] * c0j + a1 * c1j) * invj;
        aout[(size_t)grow * (NH * HDIM) + h * 64 + dt * 16 + fr] = f2bf(o);
      }
    }
  }
}

// ---------------- launch ----------------
extern "C" void kernel_launch(void* const* d_in, const int* in_sizes, int n_in,
                              void* d_out, int out_size, void* d_ws, size_t ws_size,
                              hipStream_t stream) {
  const float* x    = (const float*)d_in[0];
  const float* pcos = (const float*)d_in[1];
  const float* psin = (const float*)d_in[2];
  const float* wqkv = (const float*)d_in[3];
  const float* wo   = (const float*)d_in[4];
  float* out = (float*)d_out;

  char* ws = (char*)d_ws;
  unsigned short* xb    = (unsigned short*)ws;  ws += (size_t)S_LEN * DMODEL * 2;
  unsigned short* wqkvT = (unsigned short*)ws;  ws += (size_t)NQKV * DMODEL * 2;
  unsigned short* woT   = (unsigned short*)ws;  ws += (size_t)DMODEL * DMODEL * 2;
  float*          qkv   = (float*)ws;           ws += (size_t)S_LEN * NQKV * 4;
  unsigned short* Qh    = (unsigned short*)ws;  ws += (size_t)NH * S_LEN * HDIM * 2;
  unsigned short* Kh    = (unsigned short*)ws;  ws += (size_t)NKV * S_LEN * HDIM * 2;
  unsigned short* Vt    = (unsigned short*)ws;  ws += (size_t)NKV * HDIM * S_LEN * 2;
  unsigned short* aoutb = (unsigned short*)ws;  ws += (size_t)S_LEN * NH * HDIM * 2;

  convert_bf16<<<(S_LEN * DMODEL) / (256 * 4), 256, 0, stream>>>(x, xb, S_LEN * DMODEL);
  transpose_convert<<<dim3(NQKV / 32, DMODEL / 32, 1), dim3(32, 8), 0, stream>>>(
      wqkv, NQKV, 0, wqkvT, DMODEL, 0, DMODEL, NQKV);
  transpose_convert<<<dim3(DMODEL / 32, DMODEL / 32, 1), dim3(32, 8), 0, stream>>>(
      wo, DMODEL, 0, woT, DMODEL, 0, DMODEL, DMODEL);
  gemm_bf16<<<dim3(S_LEN / BM, NQKV / BN), 256, 0, stream>>>(xb, wqkvT, qkv, S_LEN, NQKV, DMODEL);
  rope_kernel<<<S_LEN, 256, 0, stream>>>(qkv, pcos, psin, Qh, Kh);
  transpose_convert<<<dim3(HDIM / 32, S_LEN / 32, NKV), dim3(32, 8), 0, stream>>>(
      qkv + 1280, NQKV, 64, Vt, S_LEN, (long)HDIM * S_LEN, S_LEN, HDIM);
  flash_attn<<<dim3(128, NH), 256, 0, stream>>>(Qh, Kh, Vt, aoutb);
  gemm_bf16<<<dim3(S_LEN / BM, DMODEL / BN), 256, 0, stream>>>(aoutb, woT, out, S_LEN, DMODEL, DMODEL);
}